// Round 2
// 224.460 us; speedup vs baseline: 1.0089x; 1.0089x over previous
//
#include <hip/hip_runtime.h>
#include <math.h>

#define N_     325
#define BN_    10400
#define OUTSZ_ (BN_*12)   // 124800

// R13 structure: wave-independent GRU. Each wave owns 16 rows x all 64 h-cols;
// h recurrence closes inside the wave (private LDS h-plane, stride 144B), so the
// 12-step encoder / 12-step decoder loops have NO __syncthreads (3 barriers
// total, only around weight staging; was 24). Weights live in LDS as
// pre-swizzled f16 MFMA B-fragments read via base-reg + immediate offsets
// (near-zero addressing VALU). gi/bias folded via ext-MFMA: ext B-frags hold
// W/bias in k=0..2 (enc: A-ext=[x0,x1,1]) or k=0..1 (dec: A-ext=[lv,1]);
// A-ext is zeroed on lanes>=16 so replicated 16-lane ext frag reads are safe.
// Gate algebra: 5-trans form (3 exp2 + 2 rcp), fp32 h carry, same as R11.
// LDS = 40448 B -> 4 blocks/CU. Budget: keep total (V+A)GPR <= 128.

typedef _Float16 h8v  __attribute__((ext_vector_type(8)));  // 8 f16 (4 VGPRs)
typedef float    f4v  __attribute__((ext_vector_type(4)));  // 4 fp32 acc
typedef unsigned int u32x4 __attribute__((ext_vector_type(4)));

#define L1C 1.4426950408889634f    // log2(e)
#define L2C 2.8853900817779268f    // 2*log2(e)

__device__ __forceinline__ float rcp_f(float x){ return __builtin_amdgcn_rcpf(x); }
#if __has_builtin(__builtin_amdgcn_exp2f)
__device__ __forceinline__ float exp2_f(float x){ return __builtin_amdgcn_exp2f(x); }
#else
__device__ __forceinline__ float exp2_f(float x){ return __expf(x * 0.6931471805599453f); }
#endif

__device__ __forceinline__ unsigned short f16u(float x){
    union { _Float16 h; unsigned short u; } cv; cv.h = (_Float16)x; return cv.u;
}

// ---------------- LDS layout (bytes) ----------------
// [BOFF,  +24576) 24 main B frags: (g*8+ct*2+ch)*1024 + lane*16
// [EOFF,  +3072 ) 12 ext  B frags: (g*4+ct)*256 + (lane&15)*16  (16-lane compressed)
// [HOFF,  +9216 ) per-wave h plane: w*2304; byte = row*144 + col*2  (16 rows x 64 cols f16, pad 8)
// [XOFF,  +3072 ) x packed f16 pair: row*48 + t*4        (encoder phase)
// [LWOFF, +2048 ) dec linW frags: ch*1024 + lane*16       (decoder phase, reuses XOFF)
// [WOFF,  +256  ) softmax weight per row
// [LOFF,  +256  ) lv broadcast: w*64 + idx*4
#define BOFF   0
#define EOFF   24576
#define HOFF   27648
#define XOFF   36864
#define LWOFF  36864
#define WOFF   39936
#define LOFF   40192
#define SMEMSZ 40448

#define MFMA(A,B,C) __builtin_amdgcn_mfma_f32_16x16x32_f16((A),(B),(C),0,0,0)

// Stage 192x64 f32 Whh (one cluster) into 24 pre-swizzled f16 B-frags, scaled:
// r,z rows by -log2e; n rows by -2log2e. B-frag mapping: lane holds
// col = 16*ct + (lane&15), k = 32*ch + (lane>>4)*8 + j.
__device__ __forceinline__ void stage_main(const float* __restrict__ W, char* smem, int tid)
{
    for (int it = 0; it < 24; ++it) {
        int q    = (it*256 + tid) * 2;     // even f32 index in [0,12288)
        int gc   = q >> 6;                 // weight row 0..191 (g*64+col)
        int k    = q & 63;
        int g    = gc >> 6;
        int colf = gc & 63;
        int f    = g*8 + (colf >> 4)*2 + (k >> 5);
        int lanew = ((k >> 3) & 3)*16 + (colf & 15);
        float sc = (g < 2) ? -L1C : -L2C;
        float2 wv = *(const float2*)(W + q);
        unsigned short* d = (unsigned short*)(smem + BOFF + f*1024 + lanew*16 + (k & 7)*2);
        d[0] = f16u(sc*wv.x);
        d[1] = f16u(sc*wv.y);
    }
}

// One recurrence step for one wave: 36 MFMA + gate algebra for 16 rows x 64 cols.
// bb = smem + lane*16 (main frags), eb = smem + EOFF + (lane&15)*16 (ext frags),
// wp = h-plane write base (hp + kg*576 + l15*2), hreg = fp32 carry [ct][i].
__device__ __forceinline__ void rnn_step(h8v Aeh, h8v Ah0, h8v Ah1,
                                         const char* bb, const char* eb,
                                         const float cbh[4], float (&hreg)[4][4],
                                         char* wp)
{
    const f4v Z0 = {0.f,0.f,0.f,0.f};
#pragma unroll
    for (int ct = 0; ct < 4; ++ct) {
        f4v a0 = MFMA(Aeh, *(const h8v*)(eb + ct*256),       Z0);   // r: ext (Wih,b)
        a0 = MFMA(Ah0, *(const h8v*)(bb + (ct*2   )*1024), a0);     // r: Whh ch0
        a0 = MFMA(Ah1, *(const h8v*)(bb + (ct*2+1 )*1024), a0);     // r: Whh ch1
        f4v a1 = MFMA(Aeh, *(const h8v*)(eb + (4+ct)*256),   Z0);   // z
        a1 = MFMA(Ah0, *(const h8v*)(bb + (8+ct*2 )*1024), a1);
        a1 = MFMA(Ah1, *(const h8v*)(bb + (9+ct*2 )*1024), a1);
        f4v a3 = MFMA(Aeh, *(const h8v*)(eb + (8+ct)*256),   Z0);   // n: gi part
        f4v a2 = MFMA(Ah0, *(const h8v*)(bb + (16+ct*2)*1024), Z0); // n: Whh.h
        a2 = MFMA(Ah1, *(const h8v*)(bb + (17+ct*2)*1024), a2);
#pragma unroll
        for (int i = 0; i < 4; ++i) {
            float er = exp2_f(a0[i]);
            float rr = rcp_f(1.0f + er);
            float ez = exp2_f(a1[i]);
            float en = exp2_f(fmaf(rr, a2[i] + cbh[ct], a3[i]));
            float h  = hreg[ct][i];
            float aa = 1.0f + ez;
            float den = fmaf(en, aa, aa);        // (1+en)(1+ez)
            float t1  = fmaf(-en, ez, ez);       // ez(1-en)
            float t2  = fmaf(en, h, h);          // h(1+en)
            float hnew = (t1 + t2) * rcp_f(den);
            hreg[ct][i] = hnew;
            *(_Float16*)(wp + i*144 + 32*ct) = (_Float16)hnew;
        }
    }
}

__global__ void __launch_bounds__(256, 4) krnn_kernel(
    const float* __restrict__ X,
    const float* __restrict__ eWih, const float* __restrict__ eWhh,
    const float* __restrict__ ebih, const float* __restrict__ ebhh,
    const float* __restrict__ dWih, const float* __restrict__ dWhh,
    const float* __restrict__ dbih, const float* __restrict__ dbhh,
    const float* __restrict__ linW, const float* __restrict__ linb,
    const float* __restrict__ embed, float* __restrict__ ws)
{
    __shared__ __align__(16) char smem[SMEMSZ];

    const int c    = blockIdx.y;
    const int row0 = blockIdx.x * 64;           // 64 rows per block (4 waves x 16)
    const int tid  = threadIdx.x;
    const int lane = tid & 63;
    const int w    = tid >> 6;
    const int l15  = lane & 15;
    const int kg   = lane >> 4;

    // ---------------- stage encoder weights / x / softmax / h=0 ----------------
    stage_main(eWhh + c*12288, smem, tid);

    if (tid < 192) {                            // enc ext frags: k0=Wih0,k1=Wih1,k2=bias
        int e = tid >> 4, ln = tid & 15;
        int g = e >> 2, ct = e & 3;
        int gc = g*64 + ct*16 + ln;
        float sc = (g < 2) ? -L1C : -L2C;
        float w0 = eWih[c*384 + gc*2], w1 = eWih[c*384 + gc*2 + 1];
        float bb_ = (g < 2) ? (ebih[c*192+gc] + ebhh[c*192+gc]) : ebih[c*192+gc];
        unsigned short* d = (unsigned short*)(smem + EOFF + e*256 + ln*16);
        d[0] = f16u(sc*w0); d[1] = f16u(sc*w1); d[2] = f16u(sc*bb_);
        d[3]=0; d[4]=0; d[5]=0; d[6]=0; d[7]=0;
    }
    for (int i = tid; i < 768; i += 256) {      // x: packed f16 (x0,x1) per (row,t)
        int r = i / 12, t = i - r*12;
        int rg = row0 + r; if (rg >= BN_) rg = BN_-1;
        const float* p = X + (size_t)rg*24 + t*2;
        unsigned v = (unsigned)f16u(p[0]) | ((unsigned)f16u(p[1]) << 16);
        *(unsigned*)(smem + XOFF + r*48 + t*4) = v;
    }
    if (tid < 64) {                             // softmax weight per row
        int r = row0 + tid; if (r >= BN_) r = BN_-1;
        int n = r % N_;
        float e[10], mx = -1e30f;
#pragma unroll
        for (int cc=0; cc<10; ++cc){ e[cc]=embed[n*10+cc]; mx=fmaxf(mx,e[cc]); }
        float den = 0.0f;
#pragma unroll
        for (int cc=0; cc<10; ++cc) den += exp2_f((e[cc]-mx)*L1C);
        *(float*)(smem + WOFF + tid*4) = exp2_f((e[c]-mx)*L1C) * rcp_f(den);
    }
    for (int i = tid; i < 2304; i += 256)       // zero all h planes (incl. pad)
        *(unsigned*)(smem + HOFF + i*4) = 0u;

    float cbh[4];                               // n-gate bhh, per owned col (fp32)
#pragma unroll
    for (int ct=0; ct<4; ++ct) cbh[ct] = -L2C * ebhh[c*192 + 128 + l15 + 16*ct];

    __syncthreads();                            // barrier 1/3

    float wreg[4];
#pragma unroll
    for (int i=0;i<4;++i) wreg[i] = *(const float*)(smem + WOFF + (w*16 + kg*4 + i)*4);

    char* hp = smem + HOFF + w*2304;            // private h plane
    const int rdo = l15*144 + kg*16;            // A-frag read offset (+64 for ch1)
    char* wp = hp + kg*576 + l15*2;             // gate write base
    const char* bb = smem + lane*16;            // main frag base
    const char* eb = smem + EOFF + l15*16;      // ext frag base (replicated reads)

    float hreg[4][4];
#pragma unroll
    for (int ct=0; ct<4; ++ct)
#pragma unroll
        for (int i=0;i<4;++i) hreg[ct][i] = 0.0f;

    // ---------------- encoder: 12 barrier-free steps ----------------
    for (int t = 0; t < 12; ++t) {
        unsigned xd = *(const unsigned*)(smem + XOFF + (w*16 + l15)*48 + t*4);
        union { u32x4 u; h8v h; } ae;
        ae.u.x = (lane < 16) ? xd : 0u;         // k0=x0, k1=x1
        ae.u.y = (lane < 16) ? 0x00003C00u : 0u;// k2=1.0
        ae.u.z = 0u; ae.u.w = 0u;
        h8v Ah0 = *(const h8v*)(hp + rdo);
        h8v Ah1 = *(const h8v*)(hp + rdo + 64);
        rnn_step(ae.h, Ah0, Ah1, bb, eb, cbh, hreg, wp);
    }

    // capture lv0 = f16(x[t=11].x) packed with 1.0 for the dec A-ext, before restage
    unsigned aew = (*(const unsigned*)(smem + XOFF + (w*16 + l15)*48 + 44) & 0xFFFFu)
                   | 0x3C000000u;

    __syncthreads();                            // barrier 2/3 (all enc done)

    // ---------------- stage decoder weights ----------------
    stage_main(dWhh + c*12288, smem, tid);
    if (tid < 192) {                            // dec ext frags: k0=Wih, k1=bias
        int e = tid >> 4, ln = tid & 15;
        int g = e >> 2, ct = e & 3;
        int gc = g*64 + ct*16 + ln;
        float k0, k1;
        if (g < 2) { k0 = -L1C*dWih[c*192+gc]; k1 = -L1C*(dbih[c*192+gc]+dbhh[c*192+gc]); }
        else       { k0 = -L2C*dWih[c*192+gc]; k1 = -L2C*dbih[c*192+gc]; }
        unsigned short* d = (unsigned short*)(smem + EOFF + e*256 + ln*16);
        d[0] = f16u(k0); d[1] = f16u(k1);
        d[2]=0; d[3]=0; d[4]=0; d[5]=0; d[6]=0; d[7]=0;
    }
    if (tid < 128) {                            // linW B-frags (cols replicated)
        int ch = tid >> 6, ln = tid & 63;
        int kb = ch*32 + (ln >> 4)*8;
        unsigned short* d = (unsigned short*)(smem + LWOFF + ch*1024 + ln*16);
#pragma unroll
        for (int j=0;j<8;++j) d[j] = f16u(linW[c*64 + kb + j]);
    }
#pragma unroll
    for (int ct=0; ct<4; ++ct) cbh[ct] = -L2C * dbhh[c*192 + 128 + l15 + 16*ct];
    const float lb = linb[c];
    float* __restrict__ wsc = ws + (size_t)c * OUTSZ_;

    __syncthreads();                            // barrier 3/3

    // ---------------- decoder: 12 barrier-free steps ----------------
    for (int s = 0; s < 12; ++s) {
        h8v Ah0 = *(const h8v*)(hp + rdo);
        h8v Ah1 = *(const h8v*)(hp + rdo + 64);
        if (s > 0) {
            const f4v Zv = {0.f,0.f,0.f,0.f};
            f4v av = MFMA(Ah0, *(const h8v*)(smem + LWOFF + lane*16), Zv);
            av = MFMA(Ah1, *(const h8v*)(smem + LWOFF + 1024 + lane*16), av);
            if (l15 == 0) {                     // lanes 0,16,32,48: own rows kg*4+i
#pragma unroll
                for (int i=0;i<4;++i) {
                    float lv = av[i] + lb;      // v_{s-1}
                    *(float*)(smem + LOFF + w*64 + (kg*4+i)*4) = lv;
                    int r = row0 + w*16 + kg*4 + i;
                    if (r < BN_) wsc[(size_t)r*12 + (s-1)] = wreg[i]*lv;
                }
            }
            float lvme = *(const float*)(smem + LOFF + w*64 + l15*4); // intra-wave
            aew = (unsigned)f16u(lvme) | 0x3C000000u;   // k0=lv, k1=1.0
        }
        union { u32x4 u; h8v h; } ae;
        ae.u.x = (lane < 16) ? aew : 0u;
        ae.u.y = 0u; ae.u.z = 0u; ae.u.w = 0u;
        rnn_step(ae.h, Ah0, Ah1, bb, eb, cbh, hreg, wp);
    }

    // ---------------- epilogue: v_11 from h_11 ----------------
    {
        h8v Ah0 = *(const h8v*)(hp + rdo);
        h8v Ah1 = *(const h8v*)(hp + rdo + 64);
        const f4v Zv = {0.f,0.f,0.f,0.f};
        f4v av = MFMA(Ah0, *(const h8v*)(smem + LWOFF + lane*16), Zv);
        av = MFMA(Ah1, *(const h8v*)(smem + LWOFF + 1024 + lane*16), av);
        if (l15 == 0) {
#pragma unroll
            for (int i=0;i<4;++i) {
                float lv = av[i] + lb;
                int r = row0 + w*16 + kg*4 + i;
                if (r < BN_) wsc[(size_t)r*12 + 11] = wreg[i]*lv;
            }
        }
    }
}

// Mix over clusters: out[i] = sum_c ws[c][i]. ws is 5 MB, L2/L3-hot.
__global__ void __launch_bounds__(256) mix_kernel(const float* __restrict__ ws,
                                                  float* __restrict__ out)
{
    int i = blockIdx.x * 256 + threadIdx.x;
    if (i < OUTSZ_) {
        float s = 0.0f;
#pragma unroll
        for (int c = 0; c < 10; ++c) s += ws[(size_t)c * OUTSZ_ + i];
        out[i] = s;
    }
}

extern "C" void kernel_launch(void* const* d_in, const int* in_sizes, int n_in,
                              void* d_out, int out_size, void* d_ws, size_t ws_size,
                              hipStream_t stream) {
    // 0:A 1:X 2:enc_Wih 3:enc_Whh 4:enc_bih 5:enc_bhh
    // 6:dec_Wih 7:dec_Whh 8:dec_bih 9:dec_bhh 10:lin_W 11:lin_b 12:embed
    const float* X    = (const float*)d_in[1];
    const float* eWih = (const float*)d_in[2];
    const float* eWhh = (const float*)d_in[3];
    const float* ebih = (const float*)d_in[4];
    const float* ebhh = (const float*)d_in[5];
    const float* dWih = (const float*)d_in[6];
    const float* dWhh = (const float*)d_in[7];
    const float* dbih = (const float*)d_in[8];
    const float* dbhh = (const float*)d_in[9];
    const float* linW = (const float*)d_in[10];
    const float* linb = (const float*)d_in[11];
    const float* emb  = (const float*)d_in[12];
    float* ws  = (float*)d_ws;
    float* out = (float*)d_out;

    dim3 grid((BN_ + 63) / 64, 10);   // 163 x 10 blocks, 4 independent waves each
    krnn_kernel<<<grid, dim3(256), 0, stream>>>(
        X, eWih, eWhh, ebih, ebhh, dWih, dWhh, dbih, dbhh, linW, linb, emb, ws);
    mix_kernel<<<(OUTSZ_ + 255) / 256, dim3(256), 0, stream>>>(ws, out);
}